// Round 3
// baseline (1612.429 us; speedup 1.0000x reference)
//
#include <hip/hip_runtime.h>
#include <math.h>

#define B_DIM 2048
#define V_DIM 4096
#define H_DIM 1024

// 64x64 tile, BK=16, 256 threads, 4x4 microtile per thread.
// fp32 accumulation emulating OpenBLAS sgemm GEBP: strictly k-sequential FMA
// within KC=384 panels, panel partials combined by plain fp32 add.
#define BM 64
#define BN 64
#define BK 16
#define KC 384          // OpenBLAS SGEMM_DEFAULT_Q (haswell/zen)
#define LDS_STRIDE 68   // 64+4: float4-aligned, max 2-way bank conflict (free)

enum { ACC_NONE = 0, ACC_PREACT = 1, ACC_BIAS = 2 };

// C[b,j] = sum_i A[b,i]*W[i,j] (OpenBLAS-order fp32) ; pre = bh[j] + C ;
// h = (1/(1+expf(-pre)) > U). mode: ACC_PREACT -> acc[b]+=sum h*pre (fp64),
// ACC_BIAS -> acc[b]+=sum h*bh.
__global__ __launch_bounds__(256) void gemm_h_kernel(
    const float* __restrict__ A,   // [B_DIM, V_DIM]
    const float* __restrict__ W,   // [V_DIM, H_DIM] row-major
    const float* __restrict__ bh,  // [H_DIM]
    const float* __restrict__ U,   // [B_DIM, H_DIM]
    float* __restrict__ Hout,      // [B_DIM, H_DIM]
    double* __restrict__ acc,      // [B_DIM] (atomic) or nullptr
    const int mode)
{
    __shared__ float As[BK][LDS_STRIDE];
    __shared__ float Bs[BK][LDS_STRIDE];

    const int bn = blockIdx.x * BN;
    const int bm = blockIdx.y * BM;
    const int t  = threadIdx.x;
    const int tx = t & 15;
    const int ty = t >> 4;

    const int ar  = t >> 2;  // 0..63
    const int ac4 = t & 3;   // 0..3
    const int br  = t >> 4;  // 0..15
    const int bc4 = t & 15;  // 0..15

    float tot[4][4];
    float part[4][4];
#pragma unroll
    for (int i = 0; i < 4; i++)
#pragma unroll
        for (int j = 0; j < 4; j++) { tot[i][j] = 0.0f; part[i][j] = 0.0f; }

    const float* Aptr = A + (size_t)(bm + ar) * V_DIM + ac4 * 4;
    const float* Wptr = W + (size_t)bn + bc4 * 4;

    for (int k0 = 0; k0 < V_DIM; k0 += BK) {
        float4 av = *(const float4*)(Aptr + k0);
        As[ac4 * 4 + 0][ar] = av.x;
        As[ac4 * 4 + 1][ar] = av.y;
        As[ac4 * 4 + 2][ar] = av.z;
        As[ac4 * 4 + 3][ar] = av.w;
        float4 wv = *(const float4*)(Wptr + (size_t)(k0 + br) * H_DIM);
        *(float4*)(&Bs[br][bc4 * 4]) = wv;
        __syncthreads();
#pragma unroll
        for (int k = 0; k < BK; k++) {
            float4 a4 = *(const float4*)(&As[k][ty * 4]);
            float4 b4 = *(const float4*)(&Bs[k][tx * 4]);
            float aa[4] = {a4.x, a4.y, a4.z, a4.w};
            float bb[4] = {b4.x, b4.y, b4.z, b4.w};
#pragma unroll
            for (int i = 0; i < 4; i++)
#pragma unroll
                for (int j = 0; j < 4; j++)
                    part[i][j] = fmaf(aa[i], bb[j], part[i][j]);
        }
        __syncthreads();
        if (((k0 + BK) % KC) == 0) {   // end of a KC panel: C += partial
#pragma unroll
            for (int i = 0; i < 4; i++)
#pragma unroll
                for (int j = 0; j < 4; j++) { tot[i][j] += part[i][j]; part[i][j] = 0.0f; }
        }
    }
    if ((V_DIM % KC) != 0) {           // trailing panel
#pragma unroll
        for (int i = 0; i < 4; i++)
#pragma unroll
            for (int j = 0; j < 4; j++) tot[i][j] += part[i][j];
    }

    double rowacc[4] = {0.0, 0.0, 0.0, 0.0};
#pragma unroll
    for (int i = 0; i < 4; i++) {
        const int row = bm + ty * 4 + i;
#pragma unroll
        for (int j = 0; j < 4; j++) {
            const int col = bn + tx * 4 + j;
            float bias = bh[col];
            float pre = bias + tot[i][j];                 // fp32, numpy order
            float p = 1.0f / (1.0f + expf(-pre));          // fp32 pipeline
            float u = U[(size_t)row * H_DIM + col];
            float hv = (p > u) ? 1.0f : 0.0f;
            Hout[(size_t)row * H_DIM + col] = hv;
            if (mode == ACC_PREACT) rowacc[i] += (double)hv * (double)pre;
            else if (mode == ACC_BIAS) rowacc[i] += (double)hv * (double)bias;
        }
    }
    if (mode != ACC_NONE) {
#pragma unroll
        for (int off = 8; off >= 1; off >>= 1)
#pragma unroll
            for (int i = 0; i < 4; i++)
                rowacc[i] += __shfl_xor(rowacc[i], off, 16);
        if (tx == 0) {
#pragma unroll
            for (int i = 0; i < 4; i++)
                atomicAdd(&acc[bm + ty * 4 + i], rowacc[i]);
        }
    }
}

// C[b,i] = sum_j A[b,j]*W[i,j] (h @ W^T, OpenBLAS-order fp32); sample v;
// mode==ACC_PREACT -> acc[b] += sum_i v*pre (fp64).
__global__ __launch_bounds__(256) void gemm_v_kernel(
    const float* __restrict__ A,   // [B_DIM, H_DIM]
    const float* __restrict__ W,   // [V_DIM, H_DIM] row-major
    const float* __restrict__ bv,  // [V_DIM]
    const float* __restrict__ U,   // [B_DIM, V_DIM]
    float* __restrict__ Vout,      // [B_DIM, V_DIM]
    double* __restrict__ acc,      // [B_DIM] (atomic) or nullptr
    const int mode)
{
    __shared__ float As[BK][LDS_STRIDE];
    __shared__ float Bs[BK][LDS_STRIDE];

    const int bn = blockIdx.x * BN;   // over V
    const int bm = blockIdx.y * BM;   // over B
    const int t  = threadIdx.x;
    const int tx = t & 15;
    const int ty = t >> 4;

    const int ar  = t >> 2;  // 0..63
    const int ac4 = t & 3;   // 0..3

    float tot[4][4];
    float part[4][4];
#pragma unroll
    for (int i = 0; i < 4; i++)
#pragma unroll
        for (int j = 0; j < 4; j++) { tot[i][j] = 0.0f; part[i][j] = 0.0f; }

    const float* Aptr = A + (size_t)(bm + ar) * H_DIM + ac4 * 4;
    const float* Wrow = W + (size_t)(bn + ar) * H_DIM + ac4 * 4;

    for (int k0 = 0; k0 < H_DIM; k0 += BK) {
        float4 av = *(const float4*)(Aptr + k0);
        As[ac4 * 4 + 0][ar] = av.x;
        As[ac4 * 4 + 1][ar] = av.y;
        As[ac4 * 4 + 2][ar] = av.z;
        As[ac4 * 4 + 3][ar] = av.w;
        float4 wv = *(const float4*)(Wrow + k0);   // transposed store: Bs[k][n]
        Bs[ac4 * 4 + 0][ar] = wv.x;
        Bs[ac4 * 4 + 1][ar] = wv.y;
        Bs[ac4 * 4 + 2][ar] = wv.z;
        Bs[ac4 * 4 + 3][ar] = wv.w;
        __syncthreads();
#pragma unroll
        for (int k = 0; k < BK; k++) {
            float4 a4 = *(const float4*)(&As[k][ty * 4]);
            float4 b4 = *(const float4*)(&Bs[k][tx * 4]);
            float aa[4] = {a4.x, a4.y, a4.z, a4.w};
            float bb[4] = {b4.x, b4.y, b4.z, b4.w};
#pragma unroll
            for (int i = 0; i < 4; i++)
#pragma unroll
                for (int j = 0; j < 4; j++)
                    part[i][j] = fmaf(aa[i], bb[j], part[i][j]);
        }
        __syncthreads();
        if (((k0 + BK) % KC) == 0) {
#pragma unroll
            for (int i = 0; i < 4; i++)
#pragma unroll
                for (int j = 0; j < 4; j++) { tot[i][j] += part[i][j]; part[i][j] = 0.0f; }
        }
    }
    if ((H_DIM % KC) != 0) {
#pragma unroll
        for (int i = 0; i < 4; i++)
#pragma unroll
            for (int j = 0; j < 4; j++) tot[i][j] += part[i][j];
    }

    double rowacc[4] = {0.0, 0.0, 0.0, 0.0};
#pragma unroll
    for (int i = 0; i < 4; i++) {
        const int row = bm + ty * 4 + i;
#pragma unroll
        for (int j = 0; j < 4; j++) {
            const int col = bn + tx * 4 + j;
            float pre = bv[col] + tot[i][j];
            float p = 1.0f / (1.0f + expf(-pre));
            float u = U[(size_t)row * V_DIM + col];
            float vv = (p > u) ? 1.0f : 0.0f;
            Vout[(size_t)row * V_DIM + col] = vv;
            if (mode == ACC_PREACT) rowacc[i] += (double)vv * (double)pre;
        }
    }
    if (mode != ACC_NONE) {
#pragma unroll
        for (int off = 8; off >= 1; off >>= 1)
#pragma unroll
            for (int i = 0; i < 4; i++)
                rowacc[i] += __shfl_xor(rowacc[i], off, 16);
        if (tx == 0) {
#pragma unroll
            for (int i = 0; i < 4; i++)
                atomicAdd(&acc[bm + ty * 4 + i], rowacc[i]);
        }
    }
}

// out[b] = sum_i X[b,i] * w[i] in fp64 (score term; does not feed sampling)
__global__ __launch_bounds__(256) void rowdot_kernel(
    const float* __restrict__ X, const float* __restrict__ w,
    double* __restrict__ out, const int N)
{
    const int b = blockIdx.x;
    const float* row = X + (size_t)b * N;
    double s = 0.0;
    for (int i = threadIdx.x; i < N / 4; i += blockDim.x) {
        float4 x = ((const float4*)row)[i];
        float4 ww = ((const float4*)w)[i];
        s = fma((double)x.x, (double)ww.x, s);
        s = fma((double)x.y, (double)ww.y, s);
        s = fma((double)x.z, (double)ww.z, s);
        s = fma((double)x.w, (double)ww.w, s);
    }
#pragma unroll
    for (int off = 32; off >= 1; off >>= 1) s += __shfl_xor(s, off, 64);
    __shared__ double red[4];
    if ((threadIdx.x & 63) == 0) red[threadIdx.x >> 6] = s;
    __syncthreads();
    if (threadIdx.x == 0) out[b] = red[0] + red[1] + red[2] + red[3];
}

__global__ void finalize_kernel(const double* __restrict__ vb,
                                const double* __restrict__ accpos,
                                const double* __restrict__ acchb,
                                const double* __restrict__ accneg,
                                float* __restrict__ out)
{
    int b = blockIdx.x * blockDim.x + threadIdx.x;
    if (b < B_DIM) out[b] = (float)(vb[b] + accpos[b] - acchb[b] - accneg[b]);
}

extern "C" void kernel_launch(void* const* d_in, const int* in_sizes, int n_in,
                              void* d_out, int out_size, void* d_ws, size_t ws_size,
                              hipStream_t stream) {
    (void)in_sizes; (void)n_in; (void)out_size; (void)ws_size;
    const float* visible = (const float*)d_in[0];
    const float* b_v     = (const float*)d_in[1];
    const float* b_h     = (const float*)d_in[2];
    const float* W       = (const float*)d_in[3];
    const float* u_h0    = (const float*)d_in[4];
    const float* u_v     = (const float*)d_in[5];  // [3, B, V]
    const float* u_h     = (const float*)d_in[6];  // [2, B, H]
    float* out = (float*)d_out;

    float* v_buf   = (float*)d_ws;                               // B*V floats
    float* h_buf   = v_buf + (size_t)B_DIM * V_DIM;              // B*H floats
    double* acc_pos = (double*)(h_buf + (size_t)B_DIM * H_DIM);  // B doubles
    double* acc_hb  = acc_pos + B_DIM;
    double* acc_neg = acc_hb + B_DIM;
    double* vb      = acc_neg + B_DIM;

    hipMemsetAsync(acc_pos, 0, 3 * B_DIM * sizeof(double), stream);

    dim3 blk(256);
    dim3 gh(H_DIM / BN, B_DIM / BM);   // 16 x 32 = 512 blocks
    dim3 gv(V_DIM / BN, B_DIM / BM);   // 64 x 32 = 2048 blocks

    rowdot_kernel<<<B_DIM, blk, 0, stream>>>(visible, b_v, vb, V_DIM);

    const size_t UV = (size_t)B_DIM * V_DIM;
    const size_t UH = (size_t)B_DIM * H_DIM;

    // positive phase
    gemm_h_kernel<<<gh, blk, 0, stream>>>(visible, W, b_h, u_h0, h_buf, acc_pos, ACC_PREACT);
    // k=0
    gemm_v_kernel<<<gv, blk, 0, stream>>>(h_buf, W, b_v, u_v + 0 * UV, v_buf, nullptr, ACC_NONE);
    // k=1
    gemm_h_kernel<<<gh, blk, 0, stream>>>(v_buf, W, b_h, u_h + 0 * UH, h_buf, nullptr, ACC_NONE);
    // k=2
    gemm_v_kernel<<<gv, blk, 0, stream>>>(h_buf, W, b_v, u_v + 1 * UV, v_buf, nullptr, ACC_NONE);
    // k=3: + h.b_h of final h
    gemm_h_kernel<<<gh, blk, 0, stream>>>(v_buf, W, b_h, u_h + 1 * UH, h_buf, acc_hb, ACC_BIAS);
    // k=4: + sum_i v*pre (negative score)
    gemm_v_kernel<<<gv, blk, 0, stream>>>(h_buf, W, b_v, u_v + 2 * UV, v_buf, acc_neg, ACC_PREACT);

    finalize_kernel<<<(B_DIM + 255) / 256, blk, 0, stream>>>(vb, acc_pos, acc_hb, acc_neg, out);
}

// Round 4
// 1474.570 us; speedup vs baseline: 1.0935x; 1.0935x over previous
//
#include <hip/hip_runtime.h>
#include <math.h>

#define B_DIM 2048
#define V_DIM 4096
#define H_DIM 1024

// 64x64 tile, BK=16, 256 threads, 4x4 microtile per thread.
// fp32 accumulation emulating OpenBLAS sgemm GEBP: strictly k-sequential FMA
// within KC=384 panels, panel partials combined by plain fp32 add.
// (VERIFIED bit-exact vs numpy reference in round 3 — do not alter the
//  per-element arithmetic order.)
// Round 4: double-buffered LDS + register prefetch (1 barrier/iter) to hide
// global-load latency; arithmetic untouched.
#define BM 64
#define BN 64
#define BK 16
#define KC 384          // OpenBLAS SGEMM_DEFAULT_Q (haswell/zen)
#define LDS_STRIDE 68   // 64+4: float4-aligned, max 2-way bank conflict (free)

enum { ACC_NONE = 0, ACC_PREACT = 1, ACC_BIAS = 2 };

// C[b,j] = sum_i A[b,i]*W[i,j] (OpenBLAS-order fp32) ; pre = bh[j] + C ;
// h = (1/(1+expf(-pre)) > U). mode: ACC_PREACT -> acc[b]+=sum h*pre (fp64),
// ACC_BIAS -> acc[b]+=sum h*bh.
__global__ __launch_bounds__(256) void gemm_h_kernel(
    const float* __restrict__ A,   // [B_DIM, V_DIM]
    const float* __restrict__ W,   // [V_DIM, H_DIM] row-major
    const float* __restrict__ bh,  // [H_DIM]
    const float* __restrict__ U,   // [B_DIM, H_DIM]
    float* __restrict__ Hout,      // [B_DIM, H_DIM]
    double* __restrict__ acc,      // [B_DIM] (atomic) or nullptr
    const int mode)
{
    __shared__ float As[2][BK][LDS_STRIDE];
    __shared__ float Bs[2][BK][LDS_STRIDE];

    const int bn = blockIdx.x * BN;
    const int bm = blockIdx.y * BM;
    const int t  = threadIdx.x;
    const int tx = t & 15;
    const int ty = t >> 4;

    const int ar  = t >> 2;  // 0..63
    const int ac4 = t & 3;   // 0..3
    const int br  = t >> 4;  // 0..15
    const int bc4 = t & 15;  // 0..15

    float tot[4][4];
    float part[4][4];
#pragma unroll
    for (int i = 0; i < 4; i++)
#pragma unroll
        for (int j = 0; j < 4; j++) { tot[i][j] = 0.0f; part[i][j] = 0.0f; }

    const float* Aptr = A + (size_t)(bm + ar) * V_DIM + ac4 * 4;
    const float* Wptr = W + (size_t)bn + bc4 * 4;

    // prologue: load tile 0 into regs, stage into buffer 0
    float4 av = *(const float4*)(Aptr + 0);
    float4 wv = *(const float4*)(Wptr + (size_t)br * H_DIM);
    As[0][ac4 * 4 + 0][ar] = av.x;
    As[0][ac4 * 4 + 1][ar] = av.y;
    As[0][ac4 * 4 + 2][ar] = av.z;
    As[0][ac4 * 4 + 3][ar] = av.w;
    *(float4*)(&Bs[0][br][bc4 * 4]) = wv;

    const int T = V_DIM / BK;
    int cur = 0;
    for (int it = 0; it < T; ++it) {
        __syncthreads();   // buf[cur] ready; prior reads of buf[cur^1] done
        if (it + 1 < T) {
            const int k0 = (it + 1) * BK;
            av = *(const float4*)(Aptr + k0);
            wv = *(const float4*)(Wptr + (size_t)(k0 + br) * H_DIM);
        }
#pragma unroll
        for (int k = 0; k < BK; k++) {
            float4 a4 = *(const float4*)(&As[cur][k][ty * 4]);
            float4 b4 = *(const float4*)(&Bs[cur][k][tx * 4]);
            float aa[4] = {a4.x, a4.y, a4.z, a4.w};
            float bb[4] = {b4.x, b4.y, b4.z, b4.w};
#pragma unroll
            for (int i = 0; i < 4; i++)
#pragma unroll
                for (int j = 0; j < 4; j++)
                    part[i][j] = fmaf(aa[i], bb[j], part[i][j]);
        }
        if (it + 1 < T) {
            As[cur ^ 1][ac4 * 4 + 0][ar] = av.x;
            As[cur ^ 1][ac4 * 4 + 1][ar] = av.y;
            As[cur ^ 1][ac4 * 4 + 2][ar] = av.z;
            As[cur ^ 1][ac4 * 4 + 3][ar] = av.w;
            *(float4*)(&Bs[cur ^ 1][br][bc4 * 4]) = wv;
        }
        cur ^= 1;
        if ((((it + 1) * BK) % KC) == 0) {   // end of a KC panel: C += partial
#pragma unroll
            for (int i = 0; i < 4; i++)
#pragma unroll
                for (int j = 0; j < 4; j++) { tot[i][j] += part[i][j]; part[i][j] = 0.0f; }
        }
    }
    if ((V_DIM % KC) != 0) {           // trailing panel
#pragma unroll
        for (int i = 0; i < 4; i++)
#pragma unroll
            for (int j = 0; j < 4; j++) tot[i][j] += part[i][j];
    }

    double rowacc[4] = {0.0, 0.0, 0.0, 0.0};
#pragma unroll
    for (int i = 0; i < 4; i++) {
        const int row = bm + ty * 4 + i;
#pragma unroll
        for (int j = 0; j < 4; j++) {
            const int col = bn + tx * 4 + j;
            float bias = bh[col];
            float pre = bias + tot[i][j];                 // fp32, numpy order
            float p = 1.0f / (1.0f + expf(-pre));          // fp32 pipeline
            float u = U[(size_t)row * H_DIM + col];
            float hv = (p > u) ? 1.0f : 0.0f;
            Hout[(size_t)row * H_DIM + col] = hv;
            if (mode == ACC_PREACT) rowacc[i] += (double)hv * (double)pre;
            else if (mode == ACC_BIAS) rowacc[i] += (double)hv * (double)bias;
        }
    }
    if (mode != ACC_NONE) {
#pragma unroll
        for (int off = 8; off >= 1; off >>= 1)
#pragma unroll
            for (int i = 0; i < 4; i++)
                rowacc[i] += __shfl_xor(rowacc[i], off, 16);
        if (tx == 0) {
#pragma unroll
            for (int i = 0; i < 4; i++)
                atomicAdd(&acc[bm + ty * 4 + i], rowacc[i]);
        }
    }
}

// C[b,i] = sum_j A[b,j]*W[i,j] (h @ W^T, OpenBLAS-order fp32); sample v;
// mode==ACC_PREACT -> acc[b] += sum_i v*pre (fp64).
__global__ __launch_bounds__(256) void gemm_v_kernel(
    const float* __restrict__ A,   // [B_DIM, H_DIM]
    const float* __restrict__ W,   // [V_DIM, H_DIM] row-major
    const float* __restrict__ bv,  // [V_DIM]
    const float* __restrict__ U,   // [B_DIM, V_DIM]
    float* __restrict__ Vout,      // [B_DIM, V_DIM]
    double* __restrict__ acc,      // [B_DIM] (atomic) or nullptr
    const int mode)
{
    __shared__ float As[2][BK][LDS_STRIDE];
    __shared__ float Bs[2][BK][LDS_STRIDE];

    const int bn = blockIdx.x * BN;   // over V
    const int bm = blockIdx.y * BM;   // over B
    const int t  = threadIdx.x;
    const int tx = t & 15;
    const int ty = t >> 4;

    const int ar  = t >> 2;  // 0..63
    const int ac4 = t & 3;   // 0..3

    float tot[4][4];
    float part[4][4];
#pragma unroll
    for (int i = 0; i < 4; i++)
#pragma unroll
        for (int j = 0; j < 4; j++) { tot[i][j] = 0.0f; part[i][j] = 0.0f; }

    const float* Aptr = A + (size_t)(bm + ar) * H_DIM + ac4 * 4;
    const float* Wrow = W + (size_t)(bn + ar) * H_DIM + ac4 * 4;

    // prologue: tile 0 → buffer 0
    float4 av = *(const float4*)(Aptr + 0);
    float4 wv = *(const float4*)(Wrow + 0);
    As[0][ac4 * 4 + 0][ar] = av.x;
    As[0][ac4 * 4 + 1][ar] = av.y;
    As[0][ac4 * 4 + 2][ar] = av.z;
    As[0][ac4 * 4 + 3][ar] = av.w;
    Bs[0][ac4 * 4 + 0][ar] = wv.x;
    Bs[0][ac4 * 4 + 1][ar] = wv.y;
    Bs[0][ac4 * 4 + 2][ar] = wv.z;
    Bs[0][ac4 * 4 + 3][ar] = wv.w;

    const int T = H_DIM / BK;
    int cur = 0;
    for (int it = 0; it < T; ++it) {
        __syncthreads();
        if (it + 1 < T) {
            const int k0 = (it + 1) * BK;
            av = *(const float4*)(Aptr + k0);
            wv = *(const float4*)(Wrow + k0);
        }
#pragma unroll
        for (int k = 0; k < BK; k++) {
            float4 a4 = *(const float4*)(&As[cur][k][ty * 4]);
            float4 b4 = *(const float4*)(&Bs[cur][k][tx * 4]);
            float aa[4] = {a4.x, a4.y, a4.z, a4.w};
            float bb[4] = {b4.x, b4.y, b4.z, b4.w};
#pragma unroll
            for (int i = 0; i < 4; i++)
#pragma unroll
                for (int j = 0; j < 4; j++)
                    part[i][j] = fmaf(aa[i], bb[j], part[i][j]);
        }
        if (it + 1 < T) {
            As[cur ^ 1][ac4 * 4 + 0][ar] = av.x;
            As[cur ^ 1][ac4 * 4 + 1][ar] = av.y;
            As[cur ^ 1][ac4 * 4 + 2][ar] = av.z;
            As[cur ^ 1][ac4 * 4 + 3][ar] = av.w;
            Bs[cur ^ 1][ac4 * 4 + 0][ar] = wv.x;
            Bs[cur ^ 1][ac4 * 4 + 1][ar] = wv.y;
            Bs[cur ^ 1][ac4 * 4 + 2][ar] = wv.z;
            Bs[cur ^ 1][ac4 * 4 + 3][ar] = wv.w;
        }
        cur ^= 1;
        if ((((it + 1) * BK) % KC) == 0) {
#pragma unroll
            for (int i = 0; i < 4; i++)
#pragma unroll
                for (int j = 0; j < 4; j++) { tot[i][j] += part[i][j]; part[i][j] = 0.0f; }
        }
    }
    if ((H_DIM % KC) != 0) {
#pragma unroll
        for (int i = 0; i < 4; i++)
#pragma unroll
            for (int j = 0; j < 4; j++) tot[i][j] += part[i][j];
    }

    double rowacc[4] = {0.0, 0.0, 0.0, 0.0};
#pragma unroll
    for (int i = 0; i < 4; i++) {
        const int row = bm + ty * 4 + i;
#pragma unroll
        for (int j = 0; j < 4; j++) {
            const int col = bn + tx * 4 + j;
            float pre = bv[col] + tot[i][j];
            float p = 1.0f / (1.0f + expf(-pre));
            float u = U[(size_t)row * V_DIM + col];
            float vv = (p > u) ? 1.0f : 0.0f;
            Vout[(size_t)row * V_DIM + col] = vv;
            if (mode == ACC_PREACT) rowacc[i] += (double)vv * (double)pre;
        }
    }
    if (mode != ACC_NONE) {
#pragma unroll
        for (int off = 8; off >= 1; off >>= 1)
#pragma unroll
            for (int i = 0; i < 4; i++)
                rowacc[i] += __shfl_xor(rowacc[i], off, 16);
        if (tx == 0) {
#pragma unroll
            for (int i = 0; i < 4; i++)
                atomicAdd(&acc[bm + ty * 4 + i], rowacc[i]);
        }
    }
}

// out[b] = sum_i X[b,i] * w[i] in fp64 (score term; does not feed sampling)
__global__ __launch_bounds__(256) void rowdot_kernel(
    const float* __restrict__ X, const float* __restrict__ w,
    double* __restrict__ out, const int N)
{
    const int b = blockIdx.x;
    const float* row = X + (size_t)b * N;
    double s = 0.0;
    for (int i = threadIdx.x; i < N / 4; i += blockDim.x) {
        float4 x = ((const float4*)row)[i];
        float4 ww = ((const float4*)w)[i];
        s = fma((double)x.x, (double)ww.x, s);
        s = fma((double)x.y, (double)ww.y, s);
        s = fma((double)x.z, (double)ww.z, s);
        s = fma((double)x.w, (double)ww.w, s);
    }
#pragma unroll
    for (int off = 32; off >= 1; off >>= 1) s += __shfl_xor(s, off, 64);
    __shared__ double red[4];
    if ((threadIdx.x & 63) == 0) red[threadIdx.x >> 6] = s;
    __syncthreads();
    if (threadIdx.x == 0) out[b] = red[0] + red[1] + red[2] + red[3];
}

__global__ void finalize_kernel(const double* __restrict__ vb,
                                const double* __restrict__ accpos,
                                const double* __restrict__ acchb,
                                const double* __restrict__ accneg,
                                float* __restrict__ out)
{
    int b = blockIdx.x * blockDim.x + threadIdx.x;
    if (b < B_DIM) out[b] = (float)(vb[b] + accpos[b] - acchb[b] - accneg[b]);
}

extern "C" void kernel_launch(void* const* d_in, const int* in_sizes, int n_in,
                              void* d_out, int out_size, void* d_ws, size_t ws_size,
                              hipStream_t stream) {
    (void)in_sizes; (void)n_in; (void)out_size; (void)ws_size;
    const float* visible = (const float*)d_in[0];
    const float* b_v     = (const float*)d_in[1];
    const float* b_h     = (const float*)d_in[2];
    const float* W       = (const float*)d_in[3];
    const float* u_h0    = (const float*)d_in[4];
    const float* u_v     = (const float*)d_in[5];  // [3, B, V]
    const float* u_h     = (const float*)d_in[6];  // [2, B, H]
    float* out = (float*)d_out;

    float* v_buf   = (float*)d_ws;                               // B*V floats
    float* h_buf   = v_buf + (size_t)B_DIM * V_DIM;              // B*H floats
    double* acc_pos = (double*)(h_buf + (size_t)B_DIM * H_DIM);  // B doubles
    double* acc_hb  = acc_pos + B_DIM;
    double* acc_neg = acc_hb + B_DIM;
    double* vb      = acc_neg + B_DIM;

    hipMemsetAsync(acc_pos, 0, 3 * B_DIM * sizeof(double), stream);

    dim3 blk(256);
    dim3 gh(H_DIM / BN, B_DIM / BM);   // 16 x 32 = 512 blocks
    dim3 gv(V_DIM / BN, B_DIM / BM);   // 64 x 32 = 2048 blocks

    rowdot_kernel<<<B_DIM, blk, 0, stream>>>(visible, b_v, vb, V_DIM);

    const size_t UV = (size_t)B_DIM * V_DIM;
    const size_t UH = (size_t)B_DIM * H_DIM;

    // positive phase
    gemm_h_kernel<<<gh, blk, 0, stream>>>(visible, W, b_h, u_h0, h_buf, acc_pos, ACC_PREACT);
    // k=0
    gemm_v_kernel<<<gv, blk, 0, stream>>>(h_buf, W, b_v, u_v + 0 * UV, v_buf, nullptr, ACC_NONE);
    // k=1
    gemm_h_kernel<<<gh, blk, 0, stream>>>(v_buf, W, b_h, u_h + 0 * UH, h_buf, nullptr, ACC_NONE);
    // k=2
    gemm_v_kernel<<<gv, blk, 0, stream>>>(h_buf, W, b_v, u_v + 1 * UV, v_buf, nullptr, ACC_NONE);
    // k=3: + h.b_h of final h
    gemm_h_kernel<<<gh, blk, 0, stream>>>(v_buf, W, b_h, u_h + 1 * UH, h_buf, acc_hb, ACC_BIAS);
    // k=4: + sum_i v*pre (negative score)
    gemm_v_kernel<<<gv, blk, 0, stream>>>(h_buf, W, b_v, u_v + 2 * UV, v_buf, acc_neg, ACC_PREACT);

    finalize_kernel<<<(B_DIM + 255) / 256, blk, 0, stream>>>(vb, acc_pos, acc_hb, acc_neg, out);
}